// Round 1
// baseline (303.306 us; speedup 1.0000x reference)
//
#include <hip/hip_runtime.h>
#include <hip/hip_bf16.h>
#include <stdint.h>

// GORU fused cell. B=8192, IN=1024, D=1024, CAP=10.
// Pipeline:
//   xb = bf16(x), sb = bf16(state)
//   Wt[5120][1024] bf16 = B^T of [U | W_r | W_g]   (rows 0..3071 = U cols, 3072.. = W_r cols, 4096.. = W_g cols)
//   v1/v2[10][1024] = butterfly rotation tables (exactly the reference's permuted cos/sin)
//   P[8192][3072] bf16 = { U_cx , r=sigmoid(U_rx+state@W_r+b_r) , g=sigmoid(U_gx+state@W_g+b_g) }
//   out = g*state + (1-g)*modReLU(r*butterfly(state) + U_cx)

typedef __bf16 bf16x8 __attribute__((ext_vector_type(8)));
typedef float f32x4 __attribute__((ext_vector_type(4)));

#define B_ROWS 8192
#define KDIM 1024

__device__ __forceinline__ void async16(__bf16* lds, const __hip_bfloat16* g) {
    __builtin_amdgcn_global_load_lds((const __attribute__((address_space(1))) void*)g,
                                     (__attribute__((address_space(3))) void*)lds,
                                     16, 0, 0);
}

// ---------------- prep: fp32 -> bf16 cast (row-major) ----------------
__global__ __launch_bounds__(256) void cast_kernel(const float* __restrict__ src,
                                                   __hip_bfloat16* __restrict__ dst) {
    int idx = blockIdx.x * 256 + threadIdx.x;   // one float4 per thread
    const float4 v = ((const float4*)src)[idx];
    __hip_bfloat16* d = dst + (size_t)idx * 4;
    d[0] = __float2bfloat16(v.x);
    d[1] = __float2bfloat16(v.y);
    d[2] = __float2bfloat16(v.z);
    d[3] = __float2bfloat16(v.w);
}

// ---------------- prep: transpose+cast weights into Wt[n][k] ----------------
__global__ __launch_bounds__(256) void transpose_cast(const float* __restrict__ src, // [1024][N] row-major
                                                      __hip_bfloat16* __restrict__ dst, // Wt base
                                                      int N, int rowOff) {
    __shared__ float tile[32][33];
    int n0 = blockIdx.x * 32;
    int k0 = blockIdx.y * 32;
    int tx = threadIdx.x & 31;
    int ty = threadIdx.x >> 5;  // 0..7
#pragma unroll
    for (int s = 0; s < 4; ++s) {
        int k = k0 + ty + s * 8;
        tile[ty + s * 8][tx] = src[(size_t)k * N + n0 + tx];
    }
    __syncthreads();
#pragma unroll
    for (int s = 0; s < 4; ++s) {
        int n = n0 + ty + s * 8;
        dst[(size_t)(rowOff + n) * KDIM + k0 + tx] = __float2bfloat16(tile[tx][ty + s * 8]);
    }
}

// ---------------- prep: butterfly tables ----------------
// v1[i][j] = cos(theta[i][q&511]); v2[i][j] = (q<512 ? +sin : -sin), q = m*2^i + j0,
// with j0 = j >> (10-i), m = j & ((1024>>i)-1).   (IND_PARAM decode, verified.)
__global__ __launch_bounds__(256) void table_kernel(const float* __restrict__ theta,
                                                    float* __restrict__ v1,
                                                    float* __restrict__ v2) {
    int idx = blockIdx.x * 256 + threadIdx.x;  // 10240 total
    int i = idx >> 10;
    int j = idx & 1023;
    int Q = 1024 >> i;
    int j0 = j / Q;
    int m = j & (Q - 1);
    int q = (m << i) + j0;
    float th = theta[i * 512 + (q & 511)];
    float c = cosf(th);
    float s = sinf(th);
    v1[idx] = c;
    v2[idx] = (q < 512) ? s : -s;
}

// ---------------- GEMM: 128x128 tile, BK=32, mfma 16x16x32 bf16 ----------------
// grid (24, 64): nt = blockIdx.x (24 n-tiles over virtual N=3072), mt = blockIdx.y.
// group = nt>>3: 0 -> U_cx (K=1024 over xb), 1 -> r (xb@U_r then sb@W_r), 2 -> g.
__global__ __launch_bounds__(256) void gemm_fused(const __hip_bfloat16* __restrict__ xb,
                                                  const __hip_bfloat16* __restrict__ sb,
                                                  const __hip_bfloat16* __restrict__ Wt,
                                                  const float* __restrict__ bias_r,
                                                  const float* __restrict__ bias_g,
                                                  __hip_bfloat16* __restrict__ P) {
    __shared__ __align__(16) __bf16 As[128 * 32];
    __shared__ __align__(16) __bf16 Bs[128 * 32];

    const int nt = blockIdx.x;
    const int mt = blockIdx.y;
    const int group = nt >> 3;
    const int c0 = (nt & 7) * 128;
    const int mBase = mt * 128;

    const int t = threadIdx.x;
    const int lane = t & 63;
    const int wv = t >> 6;
    const int wm = wv & 1;
    const int wn = wv >> 1;
    const int r0 = lane & 15;
    const int gq = lane >> 4;

    f32x4 acc[4][4];
    const f32x4 zero = {0.f, 0.f, 0.f, 0.f};
#pragma unroll
    for (int i = 0; i < 4; ++i)
#pragma unroll
        for (int j = 0; j < 4; ++j) acc[i][j] = zero;

    // staging decomposition: chunk = p*256 + t (16B chunks); row = chunk>>2; sub = chunk&3
    const int rowA0 = t >> 2;          // pass 0 row
    const int sub = (t & 3) * 8;       // element offset within row (8 bf16 = 16B)

    const int nphase = (group == 0) ? 1 : 2;
    for (int ph = 0; ph < nphase; ++ph) {
        const __hip_bfloat16* Ab = ph ? sb : xb;
        int bRow;
        if (group == 0)      bRow = c0;
        else if (group == 1) bRow = ph ? (3072 + c0) : (1024 + c0);
        else                 bRow = ph ? (4096 + c0) : (2048 + c0);
        const __hip_bfloat16* Bb = Wt + (size_t)bRow * KDIM;

        for (int k0 = 0; k0 < KDIM; k0 += 32) {
#pragma unroll
            for (int p = 0; p < 2; ++p) {
                int chunk = p * 256 + t;
                int row = p * 64 + rowA0;
                async16(&As[chunk * 8], Ab + (size_t)(mBase + row) * KDIM + k0 + sub);
                async16(&Bs[chunk * 8], Bb + (size_t)row * KDIM + k0 + sub);
            }
            __syncthreads();   // drains vmcnt for global_load_lds

            bf16x8 af[4], bf[4];
#pragma unroll
            for (int i = 0; i < 4; ++i)
                af[i] = *reinterpret_cast<const bf16x8*>(&As[(wm * 64 + i * 16 + r0) * 32 + gq * 8]);
#pragma unroll
            for (int j = 0; j < 4; ++j)
                bf[j] = *reinterpret_cast<const bf16x8*>(&Bs[(wn * 64 + j * 16 + r0) * 32 + gq * 8]);
#pragma unroll
            for (int i = 0; i < 4; ++i)
#pragma unroll
                for (int j = 0; j < 4; ++j)
                    acc[i][j] = __builtin_amdgcn_mfma_f32_16x16x32_bf16(af[i], bf[j], acc[i][j], 0, 0, 0);
            __syncthreads();   // protect LDS from next iteration's staging
        }
    }

    // epilogue: C/D layout col = lane&15, row = (lane>>4)*4 + reg  [m89-verified]
#pragma unroll
    for (int i = 0; i < 4; ++i) {
#pragma unroll
        for (int j = 0; j < 4; ++j) {
#pragma unroll
            for (int reg = 0; reg < 4; ++reg) {
                int row = mBase + wm * 64 + i * 16 + gq * 4 + reg;
                int cl = wn * 64 + j * 16 + r0;
                float v = acc[i][j][reg];
                int colG;
                if (group == 0) {
                    colG = c0 + cl;
                } else {
                    int c = c0 + cl;
                    float b = (group == 1) ? bias_r[c] : bias_g[c];
                    v = 1.0f / (1.0f + __expf(-(v + b)));
                    colG = ((group == 1) ? 1024 : 2048) + c;
                }
                P[(size_t)row * 3072 + colG] = __float2bfloat16(v);
            }
        }
    }
}

// ---------------- fused butterfly + modReLU + gate ----------------
// 8 rows per block; thread t owns cols {t, t+256, t+512, t+768} (2-way LDS aliasing = free).
__global__ __launch_bounds__(256) void fuse_kernel(const float* __restrict__ state,
                                                   const __hip_bfloat16* __restrict__ P,
                                                   const float* __restrict__ v1,
                                                   const float* __restrict__ v2,
                                                   const float* __restrict__ bias_c,
                                                   float* __restrict__ out) {
    __shared__ float hbuf[8][1024];
    const int t = threadIdx.x;
    const int rowBase = blockIdx.x * 8;

    float sreg[8][4];
#pragma unroll
    for (int r = 0; r < 8; ++r) {
#pragma unroll
        for (int e = 0; e < 4; ++e) {
            int col = t + 256 * e;
            float s = state[(size_t)(rowBase + r) * 1024 + col];
            hbuf[r][col] = s;
            sreg[r][e] = s;
        }
    }
    __syncthreads();

    for (int i = 0; i < 10; ++i) {
        int H = 512 >> i;
        float t1[4], t2[4];
#pragma unroll
        for (int e = 0; e < 4; ++e) {
            int j = t + 256 * e;
            t1[e] = v1[i * 1024 + j];
            t2[e] = v2[i * 1024 + (j ^ H)];
        }
        float nh[8][4];
#pragma unroll
        for (int r = 0; r < 8; ++r)
#pragma unroll
            for (int e = 0; e < 4; ++e) {
                int j = t + 256 * e;
                nh[r][e] = hbuf[r][j] * t1[e] + hbuf[r][j ^ H] * t2[e];
            }
        __syncthreads();
#pragma unroll
        for (int r = 0; r < 8; ++r)
#pragma unroll
            for (int e = 0; e < 4; ++e) hbuf[r][t + 256 * e] = nh[r][e];
        __syncthreads();
    }

#pragma unroll
    for (int r = 0; r < 8; ++r) {
#pragma unroll
        for (int e = 0; e < 4; ++e) {
            int col = t + 256 * e;
            int row = rowBase + r;
            float h = hbuf[r][col];
            const size_t pb = (size_t)row * 3072;
            float Ucx = __bfloat162float(P[pb + col]);
            float rr  = __bfloat162float(P[pb + 1024 + col]);
            float gg  = __bfloat162float(P[pb + 2048 + col]);
            float pre = rr * h + Ucx;
            float mag = fabsf(pre) + 0.001f + bias_c[col];
            float c = (pre > 0.f) ? mag : ((pre < 0.f) ? -mag : 0.f);
            out[(size_t)row * 1024 + col] = gg * sreg[r][e] + (1.f - gg) * c;
        }
    }
}

extern "C" void kernel_launch(void* const* d_in, const int* in_sizes, int n_in,
                              void* d_out, int out_size, void* d_ws, size_t ws_size,
                              hipStream_t stream) {
    const float* x      = (const float*)d_in[0];
    const float* state  = (const float*)d_in[1];
    const float* theta  = (const float*)d_in[2];
    const float* U      = (const float*)d_in[3];
    const float* W_r    = (const float*)d_in[4];
    const float* W_g    = (const float*)d_in[5];
    const float* bias_r = (const float*)d_in[6];
    const float* bias_g = (const float*)d_in[7];
    const float* bias_c = (const float*)d_in[8];
    float* out = (float*)d_out;

    // workspace layout (~90.3 MB)
    __hip_bfloat16* xb = (__hip_bfloat16*)d_ws;                       // 16 MB
    __hip_bfloat16* sb = xb + (size_t)B_ROWS * KDIM;                  // 16 MB
    __hip_bfloat16* Wt = sb + (size_t)B_ROWS * KDIM;                  // 10 MB
    __hip_bfloat16* P  = Wt + (size_t)5120 * KDIM;                    // 48 MB
    float* v1 = (float*)(P + (size_t)B_ROWS * 3072);                  // 40 KB
    float* v2 = v1 + 10 * 1024;                                       // 40 KB

    cast_kernel<<<8192, 256, 0, stream>>>(x, xb);
    cast_kernel<<<8192, 256, 0, stream>>>(state, sb);
    transpose_cast<<<dim3(96, 32), 256, 0, stream>>>(U,   Wt, 3072, 0);
    transpose_cast<<<dim3(32, 32), 256, 0, stream>>>(W_r, Wt, 1024, 3072);
    transpose_cast<<<dim3(32, 32), 256, 0, stream>>>(W_g, Wt, 1024, 4096);
    table_kernel<<<40, 256, 0, stream>>>(theta, v1, v2);
    gemm_fused<<<dim3(24, 64), 256, 0, stream>>>(xb, sb, Wt, bias_r, bias_g, P);
    fuse_kernel<<<1024, 256, 0, stream>>>(state, P, v1, v2, bias_c, out);
}